// Round 1
// baseline (56.399 us; speedup 1.0000x reference)
//
#include <hip/hip_runtime.h>
#include <stdint.h>

// Problem constants
#define N_ANCHOR 2048
#define DIM 128
#define NCAND 16          // 1 positive + 15 negatives
#define NEG_PER 15
#define NZ (N_ANCHOR * NCAND)      // 32768 candidate rows
#define INV_TEMP 3.3333333333333335f
#define LOG2E 1.4426950408889634f
#define LN2 0.6931471805599453f
#define TOTAL_ELEMS 67108864.0f    // 2048*2048*16

using bf16x8 = __attribute__((ext_vector_type(8))) __bf16;
using f32x4  = __attribute__((ext_vector_type(4))) float;

// ---------- helpers ----------
static __device__ __forceinline__ unsigned short f2bf(float f) {
  union { float f; unsigned u; } v; v.f = f;
  unsigned r = v.u + 0x7FFF + ((v.u >> 16) & 1);   // round-to-nearest-even
  return (unsigned short)(r >> 16);
}

static __device__ __forceinline__ void gload_lds16(const void* g, void* l) {
  __builtin_amdgcn_global_load_lds(
      (const __attribute__((address_space(1))) void*)g,
      (__attribute__((address_space(3))) void*)l, 16, 0, 0);
}

// ---------- kernel 1: L2-normalize rows, cast to bf16 ----------
// rows [0,2048): anchor -> a_bf ; rows [2048, 34816): z2 rows -> z_bf
// z2 row rz = j*16+k : k==0 -> positives[j], k>=1 -> negatives[j][k-1]
__global__ __launch_bounds__(256) void norm_kernel(
    const float* __restrict__ anchor, const float* __restrict__ pos,
    const float* __restrict__ neg, unsigned short* __restrict__ a_bf,
    unsigned short* __restrict__ z_bf) {
  int row  = blockIdx.x * 4 + (threadIdx.x >> 6);   // one wave per row
  int lane = threadIdx.x & 63;
  const float* src;
  unsigned short* dst;
  if (row < N_ANCHOR) {
    src = anchor + row * DIM;
    dst = a_bf + row * DIM;
  } else {
    int rz = row - N_ANCHOR;
    int j = rz >> 4, k = rz & 15;
    src = (k == 0) ? (pos + j * DIM) : (neg + (j * NEG_PER + (k - 1)) * DIM);
    dst = z_bf + rz * DIM;
  }
  float2 v = ((const float2*)src)[lane];
  float s = v.x * v.x + v.y * v.y;
  #pragma unroll
  for (int o = 32; o >= 1; o >>= 1) s += __shfl_xor(s, o);
  float scale = 1.0f / fmaxf(sqrtf(s), 1e-12f);
  ((ushort2*)dst)[lane] = make_ushort2(f2bf(v.x * scale), f2bf(v.y * scale));
}

// ---------- kernel 2: fused GEMM + BCE-loss partial reduction ----------
// C[i][c] = <a_i, z_c>; tile 128x128, 4 waves (2x2), 16x16x32 bf16 MFMA.
// LDS XOR-swizzle (16B-chunk index ^= row&7): linear global_load_lds dest +
// inverse-swizzled global SOURCE + swizzled ds_read (guide §6 G4 / rule 21).
__global__ __launch_bounds__(256) void gemm_loss_kernel(
    const unsigned short* __restrict__ a_bf,
    const unsigned short* __restrict__ z_bf,
    float* __restrict__ partial) {
  __shared__ __align__(16) unsigned short As[128 * DIM];
  __shared__ __align__(16) unsigned short Bs[128 * DIM];
  __shared__ float red[4];

  const int t    = threadIdx.x;
  const int bid  = blockIdx.x;
  const int rb   = bid >> 8;    // 16 row-blocks
  const int cb   = bid & 255;   // 256 col-blocks
  const int wave = t >> 6;
  const int lane = t & 63;

  const unsigned short* Ag = a_bf + rb * 128 * DIM;
  const unsigned short* Bg = z_bf + cb * 128 * DIM;

  // stage 32KB A + 32KB B: 2048 16B-slots each, 256 threads x 8 issues
  #pragma unroll
  for (int it = 0; it < 8; ++it) {
    int s = it * 256 + t;
    int r = s >> 4;                 // row in tile
    int c = s & 15;                 // 16B chunk in row
    int cs = c ^ (r & 7);           // inverse-swizzled SOURCE chunk
    int goff = r * DIM + cs * 8;    // in shorts
    int base = (it * 256 + wave * 64) * 8;  // wave-uniform LDS dest (shorts)
    gload_lds16(Ag + goff, As + base);
    gload_lds16(Bg + goff, Bs + base);
  }
  __syncthreads();

  const int wr  = wave >> 1, wc = wave & 1;   // wave -> 64x64 quadrant
  const int g   = lane >> 4;                  // k-group 0..3
  const int r16 = lane & 15;

  f32x4 acc[4][4];
  #pragma unroll
  for (int i = 0; i < 4; ++i)
    #pragma unroll
    for (int j = 0; j < 4; ++j) acc[i][j] = 0.0f;

  #pragma unroll
  for (int ks = 0; ks < 4; ++ks) {            // K = 128 = 4 x 32
    bf16x8 af[4], bfr[4];
    #pragma unroll
    for (int f = 0; f < 4; ++f) {
      int ar = wr * 64 + f * 16 + r16;
      int ac = (ks * 4 + g) ^ (r16 & 7);      // swizzled read chunk
      af[f] = *(const bf16x8*)(As + ar * DIM + ac * 8);
      int br = wc * 64 + f * 16 + r16;
      bfr[f] = *(const bf16x8*)(Bs + br * DIM + ac * 8);
    }
    #pragma unroll
    for (int i = 0; i < 4; ++i)
      #pragma unroll
      for (int j = 0; j < 4; ++j)
        acc[i][j] = __builtin_amdgcn_mfma_f32_16x16x32_bf16(af[i], bfr[j],
                                                            acc[i][j], 0, 0, 0);
  }

  // epilogue: l = dot/T ; elem = softplus(l) - l*[i == c>>4]
  // C/D layout (m89): col = lane&15, row = (lane>>4)*4 + reg
  const int row0 = rb * 128 + wr * 64;
  const int col0 = cb * 128 + wc * 64;
  float sum = 0.0f;
  #pragma unroll
  for (int i = 0; i < 4; ++i) {
    #pragma unroll
    for (int j = 0; j < 4; ++j) {
      int jidx = (col0 + j * 16 + r16) >> 4;  // candidate owner row j
      #pragma unroll
      for (int r = 0; r < 4; ++r) {
        float l = acc[i][j][r] * INV_TEMP;
        int gi = row0 + i * 16 + g * 4 + r;
        float sp = fmaxf(l, 0.0f) +
                   LN2 * __builtin_amdgcn_logf(
                           1.0f + __builtin_amdgcn_exp2f(-fabsf(l * LOG2E)));
        sum += sp - ((gi == jidx) ? l : 0.0f);
      }
    }
  }

  #pragma unroll
  for (int o = 32; o >= 1; o >>= 1) sum += __shfl_xor(sum, o);
  if (lane == 0) red[wave] = sum;
  __syncthreads();
  if (t == 0) partial[bid] = red[0] + red[1] + red[2] + red[3];
}

// ---------- kernel 3: final reduction ----------
__global__ __launch_bounds__(256) void reduce_kernel(
    const float* __restrict__ partial, float* __restrict__ out) {
  int t = threadIdx.x;
  float s = 0.0f;
  for (int i = t; i < 4096; i += 256) s += partial[i];
  #pragma unroll
  for (int o = 32; o >= 1; o >>= 1) s += __shfl_xor(s, o);
  __shared__ float red[4];
  if ((t & 63) == 0) red[t >> 6] = s;
  __syncthreads();
  if (t == 0) out[0] = (red[0] + red[1] + red[2] + red[3]) * (1.0f / TOTAL_ELEMS);
}

extern "C" void kernel_launch(void* const* d_in, const int* in_sizes, int n_in,
                              void* d_out, int out_size, void* d_ws, size_t ws_size,
                              hipStream_t stream) {
  const float* anchor = (const float*)d_in[0];
  const float* pos    = (const float*)d_in[1];
  const float* neg    = (const float*)d_in[2];
  char* ws = (char*)d_ws;
  unsigned short* a_bf = (unsigned short*)ws;                    // 512 KB
  unsigned short* z_bf = (unsigned short*)(ws + 524288);         // 8 MB
  float* partial       = (float*)(ws + 524288 + 8388608);        // 16 KB

  norm_kernel<<<dim3((N_ANCHOR + NZ) / 4), dim3(256), 0, stream>>>(
      anchor, pos, neg, a_bf, z_bf);
  gemm_loss_kernel<<<dim3(4096), dim3(256), 0, stream>>>(a_bf, z_bf, partial);
  reduce_kernel<<<dim3(1), dim3(256), 0, stream>>>(partial, (float*)d_out);
}

// Round 2
// 54.752 us; speedup vs baseline: 1.0301x; 1.0301x over previous
//
#include <hip/hip_runtime.h>
#include <stdint.h>

// Problem constants
#define N_ANCHOR 2048
#define DIM 128
#define NCAND 16          // 1 positive + 15 negatives
#define NEG_PER 15
#define NZ (N_ANCHOR * NCAND)      // 32768 candidate rows
#define INV_TEMP 3.3333333333333335f
#define LOG2E 1.4426950408889634f
#define LN2 0.6931471805599453f
#define TOTAL_ELEMS 67108864.0f    // 2048*2048*16
#define A_PRESCALE (INV_TEMP * LOG2E)  // folded into anchor normalization

using bf16x8 = __attribute__((ext_vector_type(8))) __bf16;
using f32x4  = __attribute__((ext_vector_type(4))) float;

// ---------- helpers ----------
static __device__ __forceinline__ unsigned short f2bf(float f) {
  union { float f; unsigned u; } v; v.f = f;
  unsigned r = v.u + 0x7FFF + ((v.u >> 16) & 1);   // round-to-nearest-even
  return (unsigned short)(r >> 16);
}

static __device__ __forceinline__ void gload_lds16(const void* g, void* l) {
  __builtin_amdgcn_global_load_lds(
      (const __attribute__((address_space(1))) void*)g,
      (__attribute__((address_space(3))) void*)l, 16, 0, 0);
}

// ---------- kernel 1: L2-normalize rows, cast to bf16 ----------
// anchor rows additionally scaled by INV_TEMP*LOG2E so the MFMA output is
// t = logit * log2(e) directly.
__global__ __launch_bounds__(256) void norm_kernel(
    const float* __restrict__ anchor, const float* __restrict__ pos,
    const float* __restrict__ neg, unsigned short* __restrict__ a_bf,
    unsigned short* __restrict__ z_bf) {
  int row  = blockIdx.x * 4 + (threadIdx.x >> 6);   // one wave per row
  int lane = threadIdx.x & 63;
  const float* src;
  unsigned short* dst;
  float pre;
  if (row < N_ANCHOR) {
    src = anchor + row * DIM;
    dst = a_bf + row * DIM;
    pre = A_PRESCALE;
  } else {
    int rz = row - N_ANCHOR;
    int j = rz >> 4, k = rz & 15;
    src = (k == 0) ? (pos + j * DIM) : (neg + (j * NEG_PER + (k - 1)) * DIM);
    dst = z_bf + rz * DIM;
    pre = 1.0f;
  }
  float2 v = ((const float2*)src)[lane];
  float s = v.x * v.x + v.y * v.y;
  #pragma unroll
  for (int o = 32; o >= 1; o >>= 1) s += __shfl_xor(s, o);
  float scale = pre / fmaxf(sqrtf(s), 1e-12f);
  ((ushort2*)dst)[lane] = make_ushort2(f2bf(v.x * scale), f2bf(v.y * scale));
}

// ---------- kernel 2: fused GEMM + BCE-loss partial reduction ----------
// t[i][c] = <a_i, z_c> (already in log2e*logit units).
// per-elem loss (in t units, scale LN2 at the very end):
//   max(t,0) + log2(1+2^-|t|) - t*[diag]
//   Σ max(t,0) = (Σt + Σ|t|)/2 ;  Σ log2(1+2^-|t|) = log2 Π (1+2^-|t|)
// LDS is stored in FRAGMENT ORDER: a wave's ds_read_b128 is base+lane*16
// (linear, conflict-free). Achieved by permuting the per-lane global SOURCE
// of global_load_lds (dest must stay linear).
__global__ __launch_bounds__(256) void gemm_loss_kernel(
    const unsigned short* __restrict__ a_bf,
    const unsigned short* __restrict__ z_bf,
    float* __restrict__ partial) {
  __shared__ __align__(16) unsigned short As[128 * DIM];
  __shared__ __align__(16) unsigned short Bs[128 * DIM];
  __shared__ float red[4];

  const int t    = threadIdx.x;
  const int bid  = blockIdx.x;
  const int rb   = bid >> 8;    // 16 row-blocks
  const int cb   = bid & 255;   // 256 col-blocks
  const int wave = t >> 6;
  const int lane = t & 63;

  const unsigned short* Ag = a_bf + rb * 128 * DIM;
  const unsigned short* Bg = z_bf + cb * 128 * DIM;

  // stage 32KB A + 32KB B in fragment order:
  // LDS 16B-slot S = it*256 + wave*64 + lane  <-  A[it*16 + (lane&15)][chunk = wave*4 + (lane>>4)]
  {
    int src_off = (lane & 15) * DIM + (wave * 4 + (lane >> 4)) * 8;  // shorts
    #pragma unroll
    for (int it = 0; it < 8; ++it) {
      int dst = (it * 256 + wave * 64) * 8;      // shorts (wave-uniform)
      gload_lds16(Ag + it * 16 * DIM + src_off, As + dst);
      gload_lds16(Bg + it * 16 * DIM + src_off, Bs + dst);
    }
  }
  __syncthreads();

  const int wr  = wave >> 1, wc = wave & 1;   // wave -> 64x64 quadrant
  const int g   = lane >> 4;                  // k-group 0..3
  const int r16 = lane & 15;

  // fragment-order read bases (shorts): byte = wr*16384 + f*4096 + ks*1024 + lane*16
  const unsigned short* Abase = As + wr * 8192 + lane * 8;
  const unsigned short* Bbase = Bs + wc * 8192 + lane * 8;

  f32x4 acc[4][4];
  #pragma unroll
  for (int i = 0; i < 4; ++i)
    #pragma unroll
    for (int j = 0; j < 4; ++j) acc[i][j] = 0.0f;

  #pragma unroll
  for (int ks = 0; ks < 4; ++ks) {            // K = 128 = 4 x 32
    bf16x8 af[4], bfr[4];
    #pragma unroll
    for (int f = 0; f < 4; ++f) {
      af[f]  = *(const bf16x8*)(Abase + ks * 512 + f * 2048);
      bfr[f] = *(const bf16x8*)(Bbase + ks * 512 + f * 2048);
    }
    #pragma unroll
    for (int i = 0; i < 4; ++i)
      #pragma unroll
      for (int j = 0; j < 4; ++j)
        acc[i][j] = __builtin_amdgcn_mfma_f32_16x16x32_bf16(af[i], bfr[j],
                                                            acc[i][j], 0, 0, 0);
  }

  // ---- epilogue: 3 VALU + 1 trans per element ----
  // 4 r-indexed partial accumulators break the fma dep chains (16 links each).
  float sumt[4]  = {0.f, 0.f, 0.f, 0.f};
  float sumab[4] = {0.f, 0.f, 0.f, 0.f};
  float prod[4]  = {1.f, 1.f, 1.f, 1.f};
  #pragma unroll
  for (int i = 0; i < 4; ++i) {
    #pragma unroll
    for (int j = 0; j < 4; ++j) {
      #pragma unroll
      for (int r = 0; r < 4; ++r) {
        float tv = acc[i][j][r];
        sumt[r]  += tv;
        sumab[r] += fabsf(tv);
        prod[r] = fmaf(prod[r], __builtin_amdgcn_exp2f(-fabsf(tv)), prod[r]);
      }
    }
  }
  float local = 0.5f * ((sumt[0] + sumt[1]) + (sumt[2] + sumt[3])
                      + (sumab[0] + sumab[1]) + (sumab[2] + sumab[3]))
              + __builtin_amdgcn_logf((prod[0] * prod[1]) * (prod[2] * prod[3]));

  // ---- diagonal fixup: only blocks with (cb>>4)==rb contain label==1 elems.
  // col owner anchor = cb*8 + wc*4 + j (independent of r16); all 16 candidate
  // slots of pair (i==j) are positives.
  if ((cb >> 4) == rb) {
    const int obase = cb * 8 + wc * 4;
    const int rbase = rb * 128 + wr * 64 + g * 4;
    float sd = 0.f;
    #pragma unroll
    for (int i = 0; i < 4; ++i) {
      #pragma unroll
      for (int r = 0; r < 4; ++r) {
        int gi = rbase + i * 16 + r;
        #pragma unroll
        for (int j = 0; j < 4; ++j)
          sd += (gi == obase + j) ? acc[i][j][r] : 0.f;
      }
    }
    local -= sd;
  }

  #pragma unroll
  for (int o = 32; o >= 1; o >>= 1) local += __shfl_xor(local, o);
  if (lane == 0) red[wave] = local;
  __syncthreads();
  if (t == 0) partial[bid] = (red[0] + red[1]) + (red[2] + red[3]);
}

// ---------- kernel 3: final reduction (applies LN2 / count) ----------
__global__ __launch_bounds__(256) void reduce_kernel(
    const float* __restrict__ partial, float* __restrict__ out) {
  int t = threadIdx.x;
  float s = 0.0f;
  for (int i = t; i < 4096; i += 256) s += partial[i];
  #pragma unroll
  for (int o = 32; o >= 1; o >>= 1) s += __shfl_xor(s, o);
  __shared__ float red[4];
  if ((t & 63) == 0) red[t >> 6] = s;
  __syncthreads();
  if (t == 0)
    out[0] = ((red[0] + red[1]) + (red[2] + red[3])) * (LN2 / TOTAL_ELEMS);
}

extern "C" void kernel_launch(void* const* d_in, const int* in_sizes, int n_in,
                              void* d_out, int out_size, void* d_ws, size_t ws_size,
                              hipStream_t stream) {
  const float* anchor = (const float*)d_in[0];
  const float* pos    = (const float*)d_in[1];
  const float* neg    = (const float*)d_in[2];
  char* ws = (char*)d_ws;
  unsigned short* a_bf = (unsigned short*)ws;                    // 512 KB
  unsigned short* z_bf = (unsigned short*)(ws + 524288);         // 8 MB
  float* partial       = (float*)(ws + 524288 + 8388608);        // 16 KB

  norm_kernel<<<dim3((N_ANCHOR + NZ) / 4), dim3(256), 0, stream>>>(
      anchor, pos, neg, a_bf, z_bf);
  gemm_loss_kernel<<<dim3(4096), dim3(256), 0, stream>>>(a_bf, z_bf, partial);
  reduce_kernel<<<dim3(1), dim3(256), 0, stream>>>(partial, (float*)d_out);
}